// Round 1
// baseline (1120.276 us; speedup 1.0000x reference)
//
#include <hip/hip_runtime.h>
#include <hip/hip_bf16.h>
#include <math.h>

typedef __bf16 bf16;
typedef __bf16 bf16x4 __attribute__((ext_vector_type(4)));
typedef __bf16 bf16x8 __attribute__((ext_vector_type(8)));
typedef unsigned short u16x8 __attribute__((ext_vector_type(8)));
typedef float f32x4 __attribute__((ext_vector_type(4)));

#define MFMA16(a, b, c) __builtin_amdgcn_mfma_f32_16x16x32_bf16((a), (b), (c), 0, 0, 0)

__device__ __forceinline__ void llds16(const void* g, void* l) {
  __builtin_amdgcn_global_load_lds(
      (const __attribute__((address_space(1))) unsigned*)g,
      (__attribute__((address_space(3))) unsigned*)l, 16, 0, 0);
}

// ---------------- transpose + fp32->bf16 convert: dst[C][R] = src[R][C] ----------------
__global__ __launch_bounds__(256) void transpose_cvt(const float* __restrict__ src,
                                                     bf16* __restrict__ dst, int R, int C) {
  __shared__ float tile[32][33];
  const int bx = blockIdx.x * 32, by = blockIdx.y * 32;
  const int tx = threadIdx.x, ty = threadIdx.y;
#pragma unroll
  for (int i = 0; i < 32; i += 8)
    tile[ty + i][tx] = src[(size_t)(by + ty + i) * C + bx + tx];
  __syncthreads();
#pragma unroll
  for (int i = 0; i < 32; i += 8)
    dst[(size_t)(bx + ty + i) * R + by + tx] = (bf16)tile[tx][ty + i];
}

// ---------------- row layernorm of inputs (fp32 [4096][2048]) -> bf16 ----------------
__global__ __launch_bounds__(256) void ln_rows(const float* __restrict__ x,
                                               bf16* __restrict__ y) {
  const int r = blockIdx.x, t = threadIdx.x;
  const float* xr = x + (size_t)r * 2048;
  f32x4 a = ((const f32x4*)xr)[t];
  f32x4 b = ((const f32x4*)xr)[t + 256];
  float s = 0.f, ss = 0.f;
#pragma unroll
  for (int j = 0; j < 4; ++j) {
    s += a[j] + b[j];
    ss += a[j] * a[j] + b[j] * b[j];
  }
#pragma unroll
  for (int m = 1; m < 64; m <<= 1) {
    s += __shfl_xor(s, m, 64);
    ss += __shfl_xor(ss, m, 64);
  }
  __shared__ float red[8];
  const int wv = t >> 6;
  if ((t & 63) == 0) { red[wv] = s; red[4 + wv] = ss; }
  __syncthreads();
  s = red[0] + red[1] + red[2] + red[3];
  ss = red[4] + red[5] + red[6] + red[7];
  const float mu = s * (1.f / 2048.f);
  const float var = ss * (1.f / 2048.f) - mu * mu;
  const float rs = rsqrtf(var + 1e-5f);
  bf16x4 o1, o2;
#pragma unroll
  for (int j = 0; j < 4; ++j) {
    o1[j] = (bf16)((a[j] - mu) * rs);
    o2[j] = (bf16)((b[j] - mu) * rs);
  }
  bf16* yr = y + (size_t)r * 2048;
  ((bf16x4*)yr)[t] = o1;
  ((bf16x4*)yr)[t + 256] = o2;
}

// ---------------- GEMM: C[M][N] = A[M][K] * B[N][K]^T (+ epilogue) ----------------
// MODE 0: C bf16 = acc + bias[col]           (qkv projection)
// MODE 1: C f32  = acc + bias[col] + res1 + res2   (mlp + residual + attention)
template <int MODE>
__global__ __launch_bounds__(256) void gemm_bt(const bf16* __restrict__ A,
                                               const bf16* __restrict__ B,
                                               void* __restrict__ Cp, int K, int lda,
                                               int ldb, int ldc,
                                               const float* __restrict__ bias,
                                               const float* __restrict__ res1,
                                               const float* __restrict__ res2) {
  __shared__ bf16 As[128 * 64];
  __shared__ bf16 Bs[128 * 64];
  const int t = threadIdx.x, w = t >> 6, l = t & 63;
  const int l16 = l & 15, lg = l >> 4;
  const int wm = w >> 1, wn = w & 1;
  const int m0 = blockIdx.y * 128, n0 = blockIdx.x * 128;
  const int arow = l >> 3, acol = (l & 7) * 8;
  f32x4 acc[4][4] = {};
  for (int k0 = 0; k0 < K; k0 += 64) {
    __syncthreads();
#pragma unroll
    for (int i = 0; i < 4; ++i) {
      const int c = i * 4 + w;
      const int row = c * 8 + arow;
      llds16(A + (size_t)(m0 + row) * lda + k0 + acol, (char*)As + c * 1024 + l * 16);
      llds16(B + (size_t)(n0 + row) * ldb + k0 + acol, (char*)Bs + c * 1024 + l * 16);
    }
    __syncthreads();
#pragma unroll
    for (int ks = 0; ks < 2; ++ks) {
      bf16x8 af[4], bfr[4];
#pragma unroll
      for (int mi = 0; mi < 4; ++mi)
        af[mi] = *(const bf16x8*)(As + (wm * 64 + mi * 16 + l16) * 64 + ks * 32 + lg * 8);
#pragma unroll
      for (int ni = 0; ni < 4; ++ni)
        bfr[ni] = *(const bf16x8*)(Bs + (wn * 64 + ni * 16 + l16) * 64 + ks * 32 + lg * 8);
#pragma unroll
      for (int mi = 0; mi < 4; ++mi)
#pragma unroll
        for (int ni = 0; ni < 4; ++ni)
          acc[mi][ni] = MFMA16(af[mi], bfr[ni], acc[mi][ni]);
    }
  }
  const int crow0 = m0 + wm * 64 + lg * 4;
  const int ccol0 = n0 + wn * 64 + l16;
  if (MODE == 0) {
    bf16* C = (bf16*)Cp;
#pragma unroll
    for (int mi = 0; mi < 4; ++mi)
#pragma unroll
      for (int ni = 0; ni < 4; ++ni) {
        const int col = ccol0 + ni * 16;
        const float bv = bias[col];
#pragma unroll
        for (int r = 0; r < 4; ++r)
          C[(size_t)(crow0 + mi * 16 + r) * ldc + col] = (bf16)(acc[mi][ni][r] + bv);
      }
  } else {
    float* C = (float*)Cp;
#pragma unroll
    for (int mi = 0; mi < 4; ++mi)
#pragma unroll
      for (int ni = 0; ni < 4; ++ni) {
        const int col = ccol0 + ni * 16;
        const float bv = bias[col];
#pragma unroll
        for (int r = 0; r < 4; ++r) {
          const size_t idx = (size_t)(crow0 + mi * 16 + r) * ldc + col;
          C[idx] = acc[mi][ni][r] + bv + res1[idx] + res2[idx];
        }
      }
  }
}

// ---------------- post1: per-head LN of q,k (in place) + exact GELU of hidden ----------------
__global__ __launch_bounds__(256) void post1(bf16* __restrict__ qkv) {
  const int r = blockIdx.x, t = threadIdx.x, w = t >> 6, l = t & 63;
  bf16* row = qkv + (size_t)r * 14336;
#pragma unroll
  for (int gi = 0; gi < 8; ++gi) {
    const int g = w + gi * 4;  // 32 groups of 128 (16 q-heads, 16 k-heads)
    bf16* p = row + g * 128 + l * 2;
    const float a = (float)p[0], b = (float)p[1];
    float s = a + b, ss = a * a + b * b;
#pragma unroll
    for (int m = 1; m < 64; m <<= 1) {
      s += __shfl_xor(s, m, 64);
      ss += __shfl_xor(ss, m, 64);
    }
    const float mu = s * (1.f / 128.f);
    const float var = ss * (1.f / 128.f) - mu * mu;
    const float rs = rsqrtf(var + 1e-5f);
    p[0] = (bf16)((a - mu) * rs);
    p[1] = (bf16)((b - mu) * rs);
  }
  bf16* hb = row + 6144;
#pragma unroll
  for (int i = 0; i < 8; ++i) {
    const int idx = t + i * 256;
    bf16x4 v = ((bf16x4*)hb)[idx];
#pragma unroll
    for (int j = 0; j < 4; ++j) {
      float f = (float)v[j];
      f = 0.5f * f * (1.f + erff(f * 0.70710678118f));
      v[j] = (bf16)f;
    }
    ((bf16x4*)hb)[idx] = v;
  }
}

// ---------------- causal flash attention ----------------
// grid: (T/64, B*H); block 256 (4 waves x 16 q-rows). KV tiles of 32.
__global__ __launch_bounds__(256) void attn_kernel(const bf16* __restrict__ qkv,
                                                   float* __restrict__ attn_out) {
  __shared__ bf16 K_lds[32][136];   // [k][d], padded (2-way bank alias only)
  __shared__ bf16 V_lds[128][40];   // transposed: [d][k]
  __shared__ bf16 P_lds[4][16][40]; // per-wave P round-trip [q][k]
  const int t = threadIdx.x, w = t >> 6, l = t & 63;
  const int l16 = l & 15, lg = l >> 4;
  const int b = blockIdx.y >> 4, h = blockIdx.y & 15;
  const int qb0 = blockIdx.x * 64;
  const int tq0 = qb0 + w * 16;
  const size_t bT = (size_t)b * 2048;
  const int LDQ = 14336;
  const size_t qoff = (size_t)h * 128;
  const size_t koff = 2048 + (size_t)h * 128;
  const size_t voff = 4096 + (size_t)h * 128;
  const float SCALE = 0.08838834764831845f;  // 128^-0.5

  bf16x8 qf[4];
  {
    const bf16* qrow = qkv + (bT + tq0 + l16) * LDQ + qoff + lg * 8;
#pragma unroll
    for (int dc = 0; dc < 4; ++dc) qf[dc] = *(const bf16x8*)(qrow + dc * 32);
  }
  float m_r[4], l_r[4];
  f32x4 accO[8] = {};
#pragma unroll
  for (int r = 0; r < 4; ++r) { m_r[r] = -1e30f; l_r[r] = 0.f; }

  const int nkv = (qb0 >> 5) + 2;
  for (int kt = 0; kt < nkv; ++kt) {
    const int kt0 = kt << 5;
    __syncthreads();
    // stage K tile [32][128]
#pragma unroll
    for (int it = 0; it < 2; ++it) {
      const int c = it * 256 + t;
      const int krow = c >> 4, c8 = (c & 15) * 8;
      *(bf16x8*)(&K_lds[krow][c8]) =
          *(const bf16x8*)(qkv + (bT + kt0 + krow) * LDQ + koff + c8);
    }
    // stage V tile transposed: V_lds[d][k], packed k-pairs as b32 writes
    {
      const int kp = (t & 15) * 2, dg = (t >> 4) * 8;
      const bf16* g0 = qkv + (bT + kt0 + kp) * LDQ + voff + dg;
      u16x8 v0 = *(const u16x8*)g0;
      u16x8 v1 = *(const u16x8*)(g0 + LDQ);
#pragma unroll
      for (int j = 0; j < 8; ++j) {
        const unsigned pk = (unsigned)v0[j] | ((unsigned)v1[j] << 16);
        *(unsigned*)(&V_lds[dg + j][kp]) = pk;
      }
    }
    __syncthreads();
    if (kt0 <= tq0 + 15) {  // wave-uniform: skip fully-masked tiles
      f32x4 sacc[2] = {};
#pragma unroll
      for (int dc = 0; dc < 4; ++dc) {
        bf16x8 kf = *(const bf16x8*)(&K_lds[l16][dc * 32 + lg * 8]);
        sacc[0] = MFMA16(qf[dc], kf, sacc[0]);
      }
#pragma unroll
      for (int dc = 0; dc < 4; ++dc) {
        bf16x8 kf = *(const bf16x8*)(&K_lds[16 + l16][dc * 32 + lg * 8]);
        sacc[1] = MFMA16(qf[dc], kf, sacc[1]);
      }
      float s0[4], s1[4];
      const bool need_mask = (kt0 + 31 > tq0);
#pragma unroll
      for (int r = 0; r < 4; ++r) {
        s0[r] = sacc[0][r] * SCALE;
        s1[r] = sacc[1][r] * SCALE;
      }
      if (need_mask) {
#pragma unroll
        for (int r = 0; r < 4; ++r) {
          const int q = tq0 + lg * 4 + r;
          if (kt0 + l16 > q) s0[r] = -1e30f;
          if (kt0 + 16 + l16 > q) s1[r] = -1e30f;
        }
      }
      float pmax[4];
#pragma unroll
      for (int r = 0; r < 4; ++r) pmax[r] = fmaxf(s0[r], s1[r]);
#pragma unroll
      for (int m = 1; m < 16; m <<= 1)
#pragma unroll
        for (int r = 0; r < 4; ++r) pmax[r] = fmaxf(pmax[r], __shfl_xor(pmax[r], m, 64));
      float fr[4];
#pragma unroll
      for (int r = 0; r < 4; ++r) {
        const float mn = fmaxf(m_r[r], pmax[r]);
        fr[r] = __expf(m_r[r] - mn);
        m_r[r] = mn;
      }
      float p0[4], p1[4], rsum[4];
#pragma unroll
      for (int r = 0; r < 4; ++r) {
        p0[r] = __expf(s0[r] - m_r[r]);
        p1[r] = __expf(s1[r] - m_r[r]);
        rsum[r] = p0[r] + p1[r];
      }
#pragma unroll
      for (int m = 1; m < 16; m <<= 1)
#pragma unroll
        for (int r = 0; r < 4; ++r) rsum[r] += __shfl_xor(rsum[r], m, 64);
#pragma unroll
      for (int r = 0; r < 4; ++r) l_r[r] = l_r[r] * fr[r] + rsum[r];
#pragma unroll
      for (int f = 0; f < 8; ++f)
#pragma unroll
        for (int r = 0; r < 4; ++r) accO[f][r] *= fr[r];
      // P round-trip: write C-layout, read A-layout
#pragma unroll
      for (int r = 0; r < 4; ++r) {
        P_lds[w][lg * 4 + r][l16] = (bf16)p0[r];
        P_lds[w][lg * 4 + r][16 + l16] = (bf16)p1[r];
      }
      bf16x8 pa = *(const bf16x8*)(&P_lds[w][l16][lg * 8]);
#pragma unroll
      for (int f = 0; f < 8; ++f) {
        bf16x8 vf = *(const bf16x8*)(&V_lds[f * 16 + l16][lg * 8]);
        accO[f] = MFMA16(pa, vf, accO[f]);
      }
    }
  }
  float inv[4];
#pragma unroll
  for (int r = 0; r < 4; ++r) inv[r] = 1.0f / l_r[r];
  float* orow = attn_out + (bT + tq0 + lg * 4) * 2048 + (size_t)h * 128 + l16;
#pragma unroll
  for (int f = 0; f < 8; ++f)
#pragma unroll
    for (int r = 0; r < 4; ++r) orow[(size_t)r * 2048 + f * 16] = accO[f][r] * inv[r];
}

// ---------------- launcher ----------------
extern "C" void kernel_launch(void* const* d_in, const int* in_sizes, int n_in,
                              void* d_out, int out_size, void* d_ws, size_t ws_size,
                              hipStream_t stream) {
  const float* inputs = (const float*)d_in[0];  // [2][2048][2048]
  const float* W_qkv = (const float*)d_in[1];   // [2048][14336]
  const float* b_qkv = (const float*)d_in[2];   // [14336]
  const float* W_mlp = (const float*)d_in[3];   // [8192][2048]
  const float* b_mlp = (const float*)d_in[4];   // [2048]
  float* out = (float*)d_out;                   // [4096][2048] fp32

  char* ws = (char*)d_ws;
  bf16* Wqkv_t = (bf16*)ws;                      // [14336][2048] 58,720,256 B
  bf16* Wmlp_t = (bf16*)(ws + 58720256);         // [2048][8192]  33,554,432 B
  bf16* x_ln = (bf16*)(ws + 92274688);           // [4096][2048]  16,777,216 B
  bf16* qkv = (bf16*)(ws + 109051904);           // [4096][14336] 117,440,512 B
  float* attn = (float*)(ws + 226492416);        // [4096][2048]  33,554,432 B
  // total 260,046,848 B

  transpose_cvt<<<dim3(14336 / 32, 2048 / 32), dim3(32, 8), 0, stream>>>(W_qkv, Wqkv_t,
                                                                         2048, 14336);
  transpose_cvt<<<dim3(2048 / 32, 8192 / 32), dim3(32, 8), 0, stream>>>(W_mlp, Wmlp_t,
                                                                        8192, 2048);
  ln_rows<<<4096, 256, 0, stream>>>(inputs, x_ln);
  gemm_bt<0><<<dim3(112, 32), 256, 0, stream>>>(x_ln, Wqkv_t, qkv, 2048, 2048, 2048,
                                                14336, b_qkv, nullptr, nullptr);
  post1<<<4096, 256, 0, stream>>>(qkv);
  attn_kernel<<<dim3(32, 32), 256, 0, stream>>>(qkv, attn);
  gemm_bt<1><<<dim3(16, 32), 256, 0, stream>>>(qkv + 6144, Wmlp_t, out, 8192, 14336,
                                               8192, 2048, b_mlp, inputs, attn);
}

// Round 3
// 960.371 us; speedup vs baseline: 1.1665x; 1.1665x over previous
//
#include <hip/hip_runtime.h>
#include <hip/hip_bf16.h>
#include <math.h>

typedef __bf16 bf16;
typedef __bf16 bf16x4 __attribute__((ext_vector_type(4)));
typedef __bf16 bf16x8 __attribute__((ext_vector_type(8)));
typedef unsigned short u16x8 __attribute__((ext_vector_type(8)));
typedef float f32x4 __attribute__((ext_vector_type(4)));

#define MFMA16(a, b, c) __builtin_amdgcn_mfma_f32_16x16x32_bf16((a), (b), (c), 0, 0, 0)

__device__ __forceinline__ void llds16(const void* g, void* l) {
  __builtin_amdgcn_global_load_lds(
      (const __attribute__((address_space(1))) unsigned*)g,
      (__attribute__((address_space(3))) unsigned*)l, 16, 0, 0);
}

// ---------------- transpose + fp32->bf16 convert: dst[C][R] = src[R][C] ----------------
__global__ __launch_bounds__(256) void transpose_cvt(const float* __restrict__ src,
                                                     bf16* __restrict__ dst, int R, int C) {
  __shared__ float tile[32][33];
  const int bx = blockIdx.x * 32, by = blockIdx.y * 32;
  const int tx = threadIdx.x, ty = threadIdx.y;
#pragma unroll
  for (int i = 0; i < 32; i += 8)
    tile[ty + i][tx] = src[(size_t)(by + ty + i) * C + bx + tx];
  __syncthreads();
#pragma unroll
  for (int i = 0; i < 32; i += 8)
    dst[(size_t)(bx + ty + i) * R + by + tx] = (bf16)tile[tx][ty + i];
}

// ---------------- row layernorm of inputs (fp32 [4096][2048]) -> bf16 ----------------
__global__ __launch_bounds__(256) void ln_rows(const float* __restrict__ x,
                                               bf16* __restrict__ y) {
  const int r = blockIdx.x, t = threadIdx.x;
  const float* xr = x + (size_t)r * 2048;
  f32x4 a = ((const f32x4*)xr)[t];
  f32x4 b = ((const f32x4*)xr)[t + 256];
  float s = 0.f, ss = 0.f;
#pragma unroll
  for (int j = 0; j < 4; ++j) {
    s += a[j] + b[j];
    ss += a[j] * a[j] + b[j] * b[j];
  }
#pragma unroll
  for (int m = 1; m < 64; m <<= 1) {
    s += __shfl_xor(s, m, 64);
    ss += __shfl_xor(ss, m, 64);
  }
  __shared__ float red[8];
  const int wv = t >> 6;
  if ((t & 63) == 0) { red[wv] = s; red[4 + wv] = ss; }
  __syncthreads();
  s = red[0] + red[1] + red[2] + red[3];
  ss = red[4] + red[5] + red[6] + red[7];
  const float mu = s * (1.f / 2048.f);
  const float var = ss * (1.f / 2048.f) - mu * mu;
  const float rs = rsqrtf(var + 1e-5f);
  bf16x4 o1, o2;
#pragma unroll
  for (int j = 0; j < 4; ++j) {
    o1[j] = (bf16)((a[j] - mu) * rs);
    o2[j] = (bf16)((b[j] - mu) * rs);
  }
  bf16* yr = y + (size_t)r * 2048;
  ((bf16x4*)yr)[t] = o1;
  ((bf16x4*)yr)[t + 256] = o2;
}

// ---------------- pipelined GEMM: C[M][N] = A[M][K] * B[N][K]^T (+ epilogue) ----------------
// 256 x BN tile, BK=32, 512 threads (8 waves as 2x4), 4-deep LDS ring, counted vmcnt,
// raw s_barrier (1/K-tile), setprio around MFMA clusters, XOR bank swizzle (rule 21).
// MODE 0: C bf16 = acc + bias[col]
// MODE 1: C f32  = acc + bias[col] + res1 + res2
template <int MODE, int BN>
__global__ __launch_bounds__(512, 2) void gemm8p(
    const bf16* __restrict__ A, const bf16* __restrict__ B, void* __restrict__ Cp,
    const int K, const int lda, const int ldb, const int ldc,
    const float* __restrict__ bias, const float* __restrict__ res1,
    const float* __restrict__ res2, const int gx) {
  constexpr int WN = BN / 4;       // per-wave N width (64 or 32)
  constexpr int NR = WN / 16;      // N frags per wave (4 or 2)
  constexpr int NRH = NR / 2;      // frags in phase 1 (2 or 1)
  constexpr int NLB = BN / 128;    // B loads per thread per tile (2 or 1)
  constexpr int BUFSZ = 8192 + NLB * 4096;  // bf16 elems per ring slot (A + B)
  __shared__ bf16 lds[4 * BUFSZ];

  const int t = threadIdx.x, w = t >> 6, l = t & 63;
  const int l16 = l & 15, lg = l >> 4;
  const int wm = w >> 2, wn = w & 3;
  // XCD-aware bijective swizzle (grid % 8 == 0)
  const int nwg = gridDim.x;
  const int id = (blockIdx.x & 7) * (nwg >> 3) + (blockIdx.x >> 3);
  const int by = id / gx, bx = id - by * gx;
  const int m0 = by * 256, n0 = bx * BN;
  const int NT = K >> 5;

  auto stage = [&](int kt) {
    bf16* Ab = lds + (size_t)(kt & 3) * BUFSZ;
    bf16* Bb = Ab + 8192;
    const int k0 = kt << 5;
    const int r4 = t >> 2;
    // linear LDS dest; source col-group pre-swizzled: cg = (t&3) ^ ((row>>1)&3)
    const int cg = (t & 3) ^ ((t >> 3) & 3);
#pragma unroll
    for (int j = 0; j < 2; ++j)
      llds16(A + (size_t)(m0 + j * 128 + r4) * lda + k0 + cg * 8, Ab + j * 4096 + t * 8);
#pragma unroll
    for (int j = 0; j < NLB; ++j)
      llds16(B + (size_t)(n0 + j * 128 + r4) * ldb + k0 + cg * 8, Bb + j * 4096 + t * 8);
  };

  f32x4 acc[8][NR] = {};
  stage(0); stage(1); stage(2);
  if constexpr (BN == 256) asm volatile("s_waitcnt vmcnt(8)" ::: "memory");
  else                     asm volatile("s_waitcnt vmcnt(6)" ::: "memory");
  __builtin_amdgcn_s_barrier();

  const int arow = wm * 128 + l16;  // + mi*16
  const int brow = wn * WN + l16;   // + ni*16
  const int slot = (lg ^ ((l16 >> 1) & 3)) * 8;  // swizzled 16B slot within 64B row

  for (int kt = 0; kt < NT; ++kt) {
    const bf16* Ab = lds + (size_t)(kt & 3) * BUFSZ;
    const bf16* Bb = Ab + 8192;
    if (kt + 3 < NT) stage(kt + 3);
    bf16x8 af[8], bfr[NR];
#pragma unroll
    for (int mi = 0; mi < 8; ++mi)
      af[mi] = *(const bf16x8*)(Ab + (arow + mi * 16) * 32 + slot);
#pragma unroll
    for (int ni = 0; ni < NRH; ++ni)
      bfr[ni] = *(const bf16x8*)(Bb + (brow + ni * 16) * 32 + slot);
    __builtin_amdgcn_s_setprio(1);
#pragma unroll
    for (int mi = 0; mi < 8; ++mi)
#pragma unroll
      for (int ni = 0; ni < NRH; ++ni)
        acc[mi][ni] = MFMA16(af[mi], bfr[ni], acc[mi][ni]);
    __builtin_amdgcn_s_setprio(0);
#pragma unroll
    for (int ni = NRH; ni < NR; ++ni)
      bfr[ni] = *(const bf16x8*)(Bb + (brow + ni * 16) * 32 + slot);
    __builtin_amdgcn_s_setprio(1);
#pragma unroll
    for (int mi = 0; mi < 8; ++mi)
#pragma unroll
      for (int ni = NRH; ni < NR; ++ni)
        acc[mi][ni] = MFMA16(af[mi], bfr[ni], acc[mi][ni]);
    __builtin_amdgcn_s_setprio(0);
    if (kt < NT - 1) {
      const int staged = (kt + 3 < NT) ? kt + 3 : NT - 1;
      const int infl = staged - (kt + 1);  // tiles allowed to stay in flight
      if (infl >= 2) {
        if constexpr (BN == 256) asm volatile("s_waitcnt vmcnt(8)" ::: "memory");
        else                     asm volatile("s_waitcnt vmcnt(6)" ::: "memory");
      } else if (infl == 1) {
        if constexpr (BN == 256) asm volatile("s_waitcnt vmcnt(4)" ::: "memory");
        else                     asm volatile("s_waitcnt vmcnt(3)" ::: "memory");
      } else {
        asm volatile("s_waitcnt vmcnt(0)" ::: "memory");
      }
      __builtin_amdgcn_s_barrier();
    }
  }

  const int crow0 = m0 + wm * 128 + lg * 4;
  const int ccol0 = n0 + wn * WN + l16;
  if constexpr (MODE == 0) {
    bf16* C = (bf16*)Cp;
#pragma unroll
    for (int ni = 0; ni < NR; ++ni) {
      const float bv = bias[ccol0 + ni * 16];
#pragma unroll
      for (int mi = 0; mi < 8; ++mi)
#pragma unroll
        for (int r = 0; r < 4; ++r)
          C[(size_t)(crow0 + mi * 16 + r) * ldc + ccol0 + ni * 16] =
              (bf16)(acc[mi][ni][r] + bv);
    }
  } else {
    float* C = (float*)Cp;
#pragma unroll
    for (int ni = 0; ni < NR; ++ni) {
      const float bv = bias[ccol0 + ni * 16];
#pragma unroll
      for (int mi = 0; mi < 8; ++mi)
#pragma unroll
        for (int r = 0; r < 4; ++r) {
          const size_t idx = (size_t)(crow0 + mi * 16 + r) * ldc + ccol0 + ni * 16;
          C[idx] = acc[mi][ni][r] + bv + res1[idx] + res2[idx];
        }
    }
  }
}

// ---------------- post1: per-head LN of q,k (in place) + exact GELU of hidden ----------------
__global__ __launch_bounds__(256) void post1(bf16* __restrict__ qkv) {
  const int r = blockIdx.x, t = threadIdx.x, w = t >> 6, l = t & 63;
  bf16* row = qkv + (size_t)r * 14336;
#pragma unroll
  for (int gi = 0; gi < 8; ++gi) {
    const int g = w + gi * 4;  // 32 groups of 128 (16 q-heads, 16 k-heads)
    bf16* p = row + g * 128 + l * 2;
    const float a = (float)p[0], b = (float)p[1];
    float s = a + b, ss = a * a + b * b;
#pragma unroll
    for (int m = 1; m < 64; m <<= 1) {
      s += __shfl_xor(s, m, 64);
      ss += __shfl_xor(ss, m, 64);
    }
    const float mu = s * (1.f / 128.f);
    const float var = ss * (1.f / 128.f) - mu * mu;
    const float rs = rsqrtf(var + 1e-5f);
    p[0] = (bf16)((a - mu) * rs);
    p[1] = (bf16)((b - mu) * rs);
  }
  bf16* hb = row + 6144;
#pragma unroll
  for (int i = 0; i < 8; ++i) {
    const int idx = t + i * 256;
    bf16x4 v = ((bf16x4*)hb)[idx];
#pragma unroll
    for (int j = 0; j < 4; ++j) {
      float f = (float)v[j];
      f = 0.5f * f * (1.f + erff(f * 0.70710678118f));
      v[j] = (bf16)f;
    }
    ((bf16x4*)hb)[idx] = v;
  }
}

// ---------------- causal flash attention ----------------
// grid: (T/64, B*H); block 256 (4 waves x 16 q-rows). KV tiles of 32.
__global__ __launch_bounds__(256) void attn_kernel(const bf16* __restrict__ qkv,
                                                   float* __restrict__ attn_out) {
  __shared__ bf16 K_lds[32][136];   // [k][d], padded (2-way bank alias only)
  __shared__ bf16 V_lds[128][40];   // transposed: [d][k]
  __shared__ bf16 P_lds[4][16][40]; // per-wave P round-trip [q][k]
  const int t = threadIdx.x, w = t >> 6, l = t & 63;
  const int l16 = l & 15, lg = l >> 4;
  const int b = blockIdx.y >> 4, h = blockIdx.y & 15;
  const int qb0 = blockIdx.x * 64;
  const int tq0 = qb0 + w * 16;
  const size_t bT = (size_t)b * 2048;
  const int LDQ = 14336;
  const size_t qoff = (size_t)h * 128;
  const size_t koff = 2048 + (size_t)h * 128;
  const size_t voff = 4096 + (size_t)h * 128;
  const float SCALE = 0.08838834764831845f;  // 128^-0.5

  bf16x8 qf[4];
  {
    const bf16* qrow = qkv + (bT + tq0 + l16) * LDQ + qoff + lg * 8;
#pragma unroll
    for (int dc = 0; dc < 4; ++dc) qf[dc] = *(const bf16x8*)(qrow + dc * 32);
  }
  float m_r[4], l_r[4];
  f32x4 accO[8] = {};
#pragma unroll
  for (int r = 0; r < 4; ++r) { m_r[r] = -1e30f; l_r[r] = 0.f; }

  const int nkv = (qb0 >> 5) + 2;
  for (int kt = 0; kt < nkv; ++kt) {
    const int kt0 = kt << 5;
    __syncthreads();
    // stage K tile [32][128]
#pragma unroll
    for (int it = 0; it < 2; ++it) {
      const int c = it * 256 + t;
      const int krow = c >> 4, c8 = (c & 15) * 8;
      *(bf16x8*)(&K_lds[krow][c8]) =
          *(const bf16x8*)(qkv + (bT + kt0 + krow) * LDQ + koff + c8);
    }
    // stage V tile transposed: V_lds[d][k], packed k-pairs as b32 writes
    {
      const int kp = (t & 15) * 2, dg = (t >> 4) * 8;
      const bf16* g0 = qkv + (bT + kt0 + kp) * LDQ + voff + dg;
      u16x8 v0 = *(const u16x8*)g0;
      u16x8 v1 = *(const u16x8*)(g0 + LDQ);
#pragma unroll
      for (int j = 0; j < 8; ++j) {
        const unsigned pk = (unsigned)v0[j] | ((unsigned)v1[j] << 16);
        *(unsigned*)(&V_lds[dg + j][kp]) = pk;
      }
    }
    __syncthreads();
    if (kt0 <= tq0 + 15) {  // wave-uniform: skip fully-masked tiles
      f32x4 sacc[2] = {};
#pragma unroll
      for (int dc = 0; dc < 4; ++dc) {
        bf16x8 kf = *(const bf16x8*)(&K_lds[l16][dc * 32 + lg * 8]);
        sacc[0] = MFMA16(qf[dc], kf, sacc[0]);
      }
#pragma unroll
      for (int dc = 0; dc < 4; ++dc) {
        bf16x8 kf = *(const bf16x8*)(&K_lds[16 + l16][dc * 32 + lg * 8]);
        sacc[1] = MFMA16(qf[dc], kf, sacc[1]);
      }
      float s0[4], s1[4];
      const bool need_mask = (kt0 + 31 > tq0);
#pragma unroll
      for (int r = 0; r < 4; ++r) {
        s0[r] = sacc[0][r] * SCALE;
        s1[r] = sacc[1][r] * SCALE;
      }
      if (need_mask) {
#pragma unroll
        for (int r = 0; r < 4; ++r) {
          const int q = tq0 + lg * 4 + r;
          if (kt0 + l16 > q) s0[r] = -1e30f;
          if (kt0 + 16 + l16 > q) s1[r] = -1e30f;
        }
      }
      float pmax[4];
#pragma unroll
      for (int r = 0; r < 4; ++r) pmax[r] = fmaxf(s0[r], s1[r]);
#pragma unroll
      for (int m = 1; m < 16; m <<= 1)
#pragma unroll
        for (int r = 0; r < 4; ++r) pmax[r] = fmaxf(pmax[r], __shfl_xor(pmax[r], m, 64));
      float fr[4];
#pragma unroll
      for (int r = 0; r < 4; ++r) {
        const float mn = fmaxf(m_r[r], pmax[r]);
        fr[r] = __expf(m_r[r] - mn);
        m_r[r] = mn;
      }
      float p0[4], p1[4], rsum[4];
#pragma unroll
      for (int r = 0; r < 4; ++r) {
        p0[r] = __expf(s0[r] - m_r[r]);
        p1[r] = __expf(s1[r] - m_r[r]);
        rsum[r] = p0[r] + p1[r];
      }
#pragma unroll
      for (int m = 1; m < 16; m <<= 1)
#pragma unroll
        for (int r = 0; r < 4; ++r) rsum[r] += __shfl_xor(rsum[r], m, 64);
#pragma unroll
      for (int r = 0; r < 4; ++r) l_r[r] = l_r[r] * fr[r] + rsum[r];
#pragma unroll
      for (int f = 0; f < 8; ++f)
#pragma unroll
        for (int r = 0; r < 4; ++r) accO[f][r] *= fr[r];
      // P round-trip: write C-layout, read A-layout
#pragma unroll
      for (int r = 0; r < 4; ++r) {
        P_lds[w][lg * 4 + r][l16] = (bf16)p0[r];
        P_lds[w][lg * 4 + r][16 + l16] = (bf16)p1[r];
      }
      bf16x8 pa = *(const bf16x8*)(&P_lds[w][l16][lg * 8]);
#pragma unroll
      for (int f = 0; f < 8; ++f) {
        bf16x8 vf = *(const bf16x8*)(&V_lds[f * 16 + l16][lg * 8]);
        accO[f] = MFMA16(pa, vf, accO[f]);
      }
    }
  }
  float inv[4];
#pragma unroll
  for (int r = 0; r < 4; ++r) inv[r] = 1.0f / l_r[r];
  float* orow = attn_out + (bT + tq0 + lg * 4) * 2048 + (size_t)h * 128 + l16;
#pragma unroll
  for (int f = 0; f < 8; ++f)
#pragma unroll
    for (int r = 0; r < 4; ++r) orow[(size_t)r * 2048 + f * 16] = accO[f][r] * inv[r];
}

// ---------------- launcher ----------------
extern "C" void kernel_launch(void* const* d_in, const int* in_sizes, int n_in,
                              void* d_out, int out_size, void* d_ws, size_t ws_size,
                              hipStream_t stream) {
  const float* inputs = (const float*)d_in[0];  // [2][2048][2048]
  const float* W_qkv = (const float*)d_in[1];   // [2048][14336]
  const float* b_qkv = (const float*)d_in[2];   // [14336]
  const float* W_mlp = (const float*)d_in[3];   // [8192][2048]
  const float* b_mlp = (const float*)d_in[4];   // [2048]
  float* out = (float*)d_out;                   // [4096][2048] fp32

  char* ws = (char*)d_ws;
  bf16* Wqkv_t = (bf16*)ws;                      // [14336][2048] 58,720,256 B
  bf16* Wmlp_t = (bf16*)(ws + 58720256);         // [2048][8192]  33,554,432 B
  bf16* x_ln = (bf16*)(ws + 92274688);           // [4096][2048]  16,777,216 B
  bf16* qkv = (bf16*)(ws + 109051904);           // [4096][14336] 117,440,512 B
  float* attn = (float*)(ws + 226492416);        // [4096][2048]  33,554,432 B
  // total 260,046,848 B

  transpose_cvt<<<dim3(14336 / 32, 2048 / 32), dim3(32, 8), 0, stream>>>(W_qkv, Wqkv_t,
                                                                         2048, 14336);
  transpose_cvt<<<dim3(2048 / 32, 8192 / 32), dim3(32, 8), 0, stream>>>(W_mlp, Wmlp_t,
                                                                        8192, 2048);
  ln_rows<<<4096, 256, 0, stream>>>(inputs, x_ln);
  // QKV: M=4096 N=14336 K=2048, 256x256 tiles -> 16x56 = 896 blocks
  gemm8p<0, 256><<<896, 512, 0, stream>>>(x_ln, Wqkv_t, qkv, 2048, 2048, 2048, 14336,
                                          b_qkv, nullptr, nullptr, 56);
  post1<<<4096, 256, 0, stream>>>(qkv);
  attn_kernel<<<dim3(32, 32), 256, 0, stream>>>(qkv, attn);
  // MLP: M=4096 N=2048 K=8192, 256x128 tiles -> 16x16 = 256 blocks
  gemm8p<1, 128><<<256, 512, 0, stream>>>(qkv + 6144, Wmlp_t, out, 8192, 14336, 8192,
                                          2048, b_mlp, inputs, attn, 16);
}